// Round 2
// baseline (2561.970 us; speedup 1.0000x reference)
//
#include <hip/hip_runtime.h>
#include <cstddef>

#define D      256
#define SEQ    1024
#define NB     2
#define NH     2
#define DH     128
#define NROWS  2048   // NB*SEQ
#define VOCAB  4096
#define TQ     16
#define TK     32
#define NSPLIT 4

// ---------------- embedding: x[b,s,o] = sum_j W_enc[o, X[b,s], j] * pos[s,j] + b_enc[o] ----------------
__global__ __launch_bounds__(256) void k_embed(const int* __restrict__ X, const float* __restrict__ We,
                                               const float* __restrict__ be, float* __restrict__ x){
  int row = blockIdx.x;          // b*1024 + s
  int s   = row & (SEQ - 1);
  int t   = X[row];
  __shared__ __align__(16) float pos[D];
  __shared__ __align__(16) float xo[D];
  int tid = threadIdx.x;
  {
    int j = tid & 127;
    float invf = __expf(-(float)j * (9.210340371976184f / 128.0f)); // 10000^(-j/128)
    float ang  = (2.0f - (float)s) * invf;                          // positions = B - arange(S)
    pos[tid] = (tid < 128) ? sinf(ang) : cosf(ang);
  }
  __syncthreads();
  int wave = tid >> 6, lane = tid & 63;
  float4 pv = ((const float4*)pos)[lane];
  for (int o = wave; o < D; o += 4){
    const float* rowp = We + ((size_t)o * VOCAB + (size_t)t) * D;  // W_enc[o][t][*], 1KB aligned
    float4 w4 = ((const float4*)rowp)[lane];
    float a = w4.x*pv.x + w4.y*pv.y + w4.z*pv.z + w4.w*pv.w;
    #pragma unroll
    for (int off = 32; off > 0; off >>= 1) a += __shfl_down(a, off);
    if (lane == 0) xo[o] = a + be[o];
  }
  __syncthreads();
  if (tid < 64) ((float4*)(x + (size_t)row * D))[tid] = ((const float4*)xo)[tid];
}

// ---------------- qkv projections: blockIdx.y selects matrix; 16 rows per block ----------------
__global__ __launch_bounds__(256) void k_qkv(const float* __restrict__ x, const float* __restrict__ Wq,
                                             const float* __restrict__ Wk, const float* __restrict__ Wv,
                                             float* __restrict__ q, float* __restrict__ k, float* __restrict__ v){
  __shared__ __align__(16) float xs[16][D];
  int tid = threadIdx.x;
  int r0  = blockIdx.x * 16;
  const float* W = (blockIdx.y == 0) ? Wq : (blockIdx.y == 1) ? Wk : Wv;
  float* outp    = (blockIdx.y == 0) ? q  : (blockIdx.y == 1) ? k  : v;
  for (int i = tid; i < 16 * D; i += 256) xs[i >> 8][i & 255] = x[(size_t)r0 * D + i];
  __syncthreads();
  float acc[16];
  #pragma unroll
  for (int r = 0; r < 16; r++) acc[r] = 0.f;
  for (int kk = 0; kk < D; kk += 4){
    float4 xv[16];
    #pragma unroll
    for (int r = 0; r < 16; r++) xv[r] = *(const float4*)&xs[r][kk];
    #pragma unroll
    for (int u = 0; u < 4; u++){
      float w = W[(size_t)(kk + u) * D + tid];
      #pragma unroll
      for (int r = 0; r < 16; r++){
        float xvu = (u == 0) ? xv[r].x : (u == 1) ? xv[r].y : (u == 2) ? xv[r].z : xv[r].w;
        acc[r] += xvu * w;
      }
    }
  }
  #pragma unroll
  for (int r = 0; r < 16; r++) outp[(size_t)(r0 + r) * D + tid] = acc[r];
}

// ---------------- flash attention with k-split; partials combined by k_combine ----------------
// o_part: [NSPLIT][NROWS][D] unnormalized; ml: [NSPLIT][NROWS][NH][2] = (m, l)
__global__ __launch_bounds__(256) void k_attn(const float* __restrict__ qg, const float* __restrict__ kgl,
                                              const float* __restrict__ vg, float* __restrict__ o_part,
                                              float* __restrict__ ml){
  int qt = blockIdx.x, bh = blockIdx.y, sp = blockIdx.z;
  int b = bh >> 1, h = bh & 1;
  int tid  = threadIdx.x;
  int base = b * SEQ;
  int qmax = qt * TQ + TQ - 1;
  int NT   = qmax / TK + 1;                 // causal: tiles covering keys 0..qmax
  int tps  = (NT + NSPLIT - 1) / NSPLIT;
  int t0   = sp * tps;
  int t1   = min(NT, t0 + tps);
  int qo   = tid >> 4;                      // 0..15 : q row in tile
  int l4   = tid & 15;
  int rowg = base + qt * TQ + qo;

  if (t0 >= t1){                            // empty split: mark l=0 (block-uniform, pre-barrier)
    if (l4 == 0){
      float* mp = ml + (((size_t)sp * NROWS + rowg) * NH + h) * 2;
      mp[0] = -1e30f; mp[1] = 0.f;
    }
    return;
  }

  __shared__ __align__(16) float Qs[TQ][DH + 4];   // +4 pad
  __shared__ __align__(16) float KT[DH][TK + 4];   // K transposed, stride 36
  __shared__ __align__(16) float Vs[TK][DH];
  __shared__ __align__(16) float Ps[TQ][TK + 4];   // stride 36

  for (int i = tid; i < TQ * DH; i += 256){
    int r = i >> 7, d = i & 127;
    Qs[r][d] = qg[(size_t)(base + qt * TQ + r) * D + h * DH + d];
  }

  float m_i = -1e30f, l_i = 0.f;
  float4 accA = {0.f,0.f,0.f,0.f}, accB = {0.f,0.f,0.f,0.f};
  const float scale = 0.08838834764831845f; // 1/sqrt(128)

  for (int kt = t0; kt < t1; kt++){
    __syncthreads();                        // protect KT/Vs/Ps from previous iteration readers
    for (int i = tid; i < TK * DH; i += 256){
      int r = i >> 7, d = i & 127;
      size_t gi = (size_t)(base + kt * TK + r) * D + h * DH + d;
      KT[d][r] = kgl[gi];
      Vs[r][d] = vg[gi];
    }
    __syncthreads();
    // scores: thread (qo, cols 2*l4, 2*l4+1), outer product over d
    int c0 = l4 * 2;
    float s0 = 0.f, s1 = 0.f;
    for (int d = 0; d < DH; d++){
      float  qv = Qs[qo][d];
      float2 k2 = *(const float2*)&KT[d][c0];
      s0 += qv * k2.x;
      s1 += qv * k2.y;
    }
    s0 *= scale; s1 *= scale;
    int kidx = kt * TK + c0;
    int qidx = qt * TQ + qo;
    if (kidx     > qidx) s0 = -1e30f;
    if (kidx + 1 > qidx) s1 = -1e30f;
    // online softmax, team = 16 lanes of row qo (within one wave)
    float tm = fmaxf(s0, s1);
    #pragma unroll
    for (int off = 1; off < 16; off <<= 1) tm = fmaxf(tm, __shfl_xor(tm, off));
    float newm  = fmaxf(m_i, tm);
    float alpha = __expf(m_i - newm);
    float p0 = __expf(s0 - newm), p1 = __expf(s1 - newm);
    float ts = p0 + p1;
    #pragma unroll
    for (int off = 1; off < 16; off <<= 1) ts += __shfl_xor(ts, off);
    l_i = l_i * alpha + ts;
    m_i = newm;
    *(float2*)&Ps[qo][c0] = make_float2(p0, p1);
    accA.x *= alpha; accA.y *= alpha; accA.z *= alpha; accA.w *= alpha;
    accB.x *= alpha; accB.y *= alpha; accB.z *= alpha; accB.w *= alpha;
    __syncthreads();
    // PV: thread (qo, d-slices [4*l4, 4*l4+3] and [64+4*l4, ...])
    int dA = l4 * 4, dB = 64 + l4 * 4;
    for (int kk = 0; kk < TK; kk++){
      float  p  = Ps[qo][kk];
      float4 va = *(const float4*)&Vs[kk][dA];
      float4 vb = *(const float4*)&Vs[kk][dB];
      accA.x += p * va.x; accA.y += p * va.y; accA.z += p * va.z; accA.w += p * va.w;
      accB.x += p * vb.x; accB.y += p * vb.y; accB.z += p * vb.z; accB.w += p * vb.w;
    }
  }
  float* op = o_part + ((size_t)sp * NROWS + rowg) * D + h * DH;
  *(float4*)&op[l4 * 4]      = accA;
  *(float4*)&op[64 + l4 * 4] = accB;
  if (l4 == 0){
    float* mp = ml + (((size_t)sp * NROWS + rowg) * NH + h) * 2;
    mp[0] = m_i; mp[1] = l_i;
  }
}

__global__ __launch_bounds__(256) void k_combine(const float* __restrict__ o_part, const float* __restrict__ ml,
                                                 float* __restrict__ aout){
  int row = blockIdx.x;
  int d   = threadIdx.x;
  int h   = d >> 7;
  float m[NSPLIT], l[NSPLIT];
  float mstar = -1e30f;
  #pragma unroll
  for (int s = 0; s < NSPLIT; s++){
    const float* mp = ml + (((size_t)s * NROWS + row) * NH + h) * 2;
    m[s] = mp[0]; l[s] = mp[1];
    mstar = fmaxf(mstar, m[s]);
  }
  float L = 0.f, o = 0.f;
  #pragma unroll
  for (int s = 0; s < NSPLIT; s++){
    float w = __expf(m[s] - mstar);
    L += l[s] * w;
    if (l[s] > 0.f) o += w * o_part[((size_t)s * NROWS + row) * D + d];
  }
  aout[(size_t)row * D + d] = o / L;
}

// ---------------- fused Wo projection + SiLU MLP + residual; 8 rows per block ----------------
__global__ __launch_bounds__(256) void k_womlp(const float* __restrict__ ain, const float* __restrict__ Wo,
                                               const float* __restrict__ W1, const float* __restrict__ W2,
                                               float* __restrict__ x){
  __shared__ __align__(16) float os[8][D];
  __shared__ __align__(16) float as[8][D];
  __shared__ __align__(16) float hs[8][2 * D];
  int tid = threadIdx.x;
  int r0  = blockIdx.x * 8;
  for (int i = tid; i < 8 * D; i += 256) os[i >> 8][i & 255] = ain[(size_t)r0 * D + i];
  __syncthreads();
  { // a = o @ Wo
    float acc[8];
    #pragma unroll
    for (int r = 0; r < 8; r++) acc[r] = 0.f;
    for (int kk = 0; kk < D; kk += 4){
      float4 xv[8];
      #pragma unroll
      for (int r = 0; r < 8; r++) xv[r] = *(const float4*)&os[r][kk];
      #pragma unroll
      for (int u = 0; u < 4; u++){
        float w = Wo[(size_t)(kk + u) * D + tid];
        #pragma unroll
        for (int r = 0; r < 8; r++){
          float xvu = (u == 0) ? xv[r].x : (u == 1) ? xv[r].y : (u == 2) ? xv[r].z : xv[r].w;
          acc[r] += xvu * w;
        }
      }
    }
    #pragma unroll
    for (int r = 0; r < 8; r++) as[r][tid] = acc[r];
  }
  __syncthreads();
  { // h = silu(a @ W1), W1: [D][2D]
    float a0[8], a1[8];
    #pragma unroll
    for (int r = 0; r < 8; r++){ a0[r] = 0.f; a1[r] = 0.f; }
    for (int j = 0; j < D; j += 4){
      float4 xv[8];
      #pragma unroll
      for (int r = 0; r < 8; r++) xv[r] = *(const float4*)&as[r][j];
      #pragma unroll
      for (int u = 0; u < 4; u++){
        float w0 = W1[(size_t)(j + u) * 2 * D + tid];
        float w1 = W1[(size_t)(j + u) * 2 * D + tid + 256];
        #pragma unroll
        for (int r = 0; r < 8; r++){
          float av = (u == 0) ? xv[r].x : (u == 1) ? xv[r].y : (u == 2) ? xv[r].z : xv[r].w;
          a0[r] += av * w0; a1[r] += av * w1;
        }
      }
    }
    #pragma unroll
    for (int r = 0; r < 8; r++){
      float h0 = a0[r], h1 = a1[r];
      hs[r][tid]       = h0 / (1.f + __expf(-h0));
      hs[r][tid + 256] = h1 / (1.f + __expf(-h1));
    }
  }
  __syncthreads();
  { // x += h @ W2, W2: [2D][D]
    float acc[8];
    #pragma unroll
    for (int r = 0; r < 8; r++) acc[r] = 0.f;
    for (int mm = 0; mm < 2 * D; mm += 4){
      float4 xv[8];
      #pragma unroll
      for (int r = 0; r < 8; r++) xv[r] = *(const float4*)&hs[r][mm];
      #pragma unroll
      for (int u = 0; u < 4; u++){
        float w = W2[(size_t)(mm + u) * D + tid];
        #pragma unroll
        for (int r = 0; r < 8; r++){
          float hv = (u == 0) ? xv[r].x : (u == 1) ? xv[r].y : (u == 2) ? xv[r].z : xv[r].w;
          acc[r] += hv * w;
        }
      }
    }
    #pragma unroll
    for (int r = 0; r < 8; r++){
      size_t idx = (size_t)(r0 + r) * D + tid;
      x[idx] = x[idx] + acc[r];
    }
  }
}

// ---------------- decoder: out[row, :] = x[row, :] @ W_dec, fp32 out; 16 rows x 256 cols per block ----------------
__global__ __launch_bounds__(256) void k_dec(const float* __restrict__ x, const float* __restrict__ Wd,
                                             float* __restrict__ out){
  __shared__ __align__(16) float xs[16][D];
  int tid = threadIdx.x;
  int r0  = blockIdx.y * 16;
  int col = blockIdx.x * 256 + tid;       // 0..4095
  for (int i = tid; i < 16 * D; i += 256) xs[i >> 8][i & 255] = x[(size_t)r0 * D + i];
  __syncthreads();
  float acc[16];
  #pragma unroll
  for (int r = 0; r < 16; r++) acc[r] = 0.f;
  for (int kk = 0; kk < D; kk += 4){
    float4 xv[16];
    #pragma unroll
    for (int r = 0; r < 16; r++) xv[r] = *(const float4*)&xs[r][kk];
    #pragma unroll
    for (int u = 0; u < 4; u++){
      float w = Wd[(size_t)(kk + u) * VOCAB + col];
      #pragma unroll
      for (int r = 0; r < 16; r++){
        float xvu = (u == 0) ? xv[r].x : (u == 1) ? xv[r].y : (u == 2) ? xv[r].z : xv[r].w;
        acc[r] += xvu * w;
      }
    }
  }
  #pragma unroll
  for (int r = 0; r < 16; r++) out[(size_t)(r0 + r) * VOCAB + col] = acc[r];
}

extern "C" void kernel_launch(void* const* d_in, const int* in_sizes, int n_in,
                              void* d_out, int out_size, void* d_ws, size_t ws_size,
                              hipStream_t stream){
  const int*   X  = (const int*)d_in[0];
  const float* We = (const float*)d_in[1];
  const float* be = (const float*)d_in[2];
  const float* Wq = (const float*)d_in[3];
  const float* Wk = (const float*)d_in[4];
  const float* Wv = (const float*)d_in[5];
  const float* Wo = (const float*)d_in[6];
  const float* W1 = (const float*)d_in[7];
  const float* W2 = (const float*)d_in[8];
  const float* Wd = (const float*)d_in[9];
  float* out = (float*)d_out;

  float* ws = (float*)d_ws;
  const size_t NX = (size_t)NROWS * D;            // 524288 floats
  float* x  = ws;                                  // [NROWS][D]
  float* q  = ws + NX;
  float* k  = ws + 2 * NX;
  float* v  = ws + 3 * NX;
  float* a  = ws + 4 * NX;
  float* op = ws + 5 * NX;                         // [NSPLIT][NROWS][D]
  float* ml = ws + (5 + NSPLIT) * NX;              // [NSPLIT][NROWS][NH][2]

  k_embed<<<NROWS, 256, 0, stream>>>(X, We, be, x);
  for (int l = 0; l < 6; l++){
    k_qkv<<<dim3(NROWS / 16, 3), 256, 0, stream>>>(x, Wq + (size_t)l * D * D, Wk + (size_t)l * D * D,
                                                   Wv + (size_t)l * D * D, q, k, v);
    k_attn<<<dim3(SEQ / TQ, NB * NH, NSPLIT), 256, 0, stream>>>(q, k, v, op, ml);
    k_combine<<<NROWS, 256, 0, stream>>>(op, ml, a);
    k_womlp<<<NROWS / 8, 256, 0, stream>>>(a, Wo + (size_t)l * D * D, W1 + (size_t)l * D * 2 * D,
                                           W2 + (size_t)l * 2 * D * D, x);
  }
  k_dec<<<dim3(VOCAB / 256, NROWS / 16), 256, 0, stream>>>(x, Wd, out);
}